// Round 3
// baseline (287.589 us; speedup 1.0000x reference)
//
#include <hip/hip_runtime.h>
#include <hip/hip_bf16.h>

// Talking-heads attention + GFSA reaction, MI355X (gfx950).
//   attn_final = (1-2λ)A + 3λ A²  applied to v:
//   ctx = (1-2λ)(A@v) + 3λ A@(A@v)   -- never forms A@A.
// R2->R3: global_load_lds(16B) staging w/ pre-swizzled global source in all
// GEMMs; split-K x4 (atomicAdd f32) for the skinny GEMM3/GEMM4; pk_bf16 stores.

typedef __bf16 bf16x8 __attribute__((ext_vector_type(8)));
typedef float f32x4 __attribute__((ext_vector_type(4)));

#define DI __device__ __forceinline__

DI unsigned short f2bf(float f) {
  union { float f; unsigned u; } x; x.f = f;
  unsigned r = x.u + 0x7FFF + ((x.u >> 16) & 1);   // RNE
  return (unsigned short)(r >> 16);
}
DI float bf2f(unsigned short u) {
  union { unsigned u; float f; } x; x.u = ((unsigned)u) << 16; return x.f;
}
DI unsigned pk_bf16(float a, float b) {   // packs (a,b) -> 2xbf16, RNE
  unsigned r;
  asm("v_cvt_pk_bf16_f32 %0, %1, %2" : "=v"(r) : "v"(a), "v"(b));
  return r;
}
DI void gload16(const unsigned short* g, unsigned short* l) {
  __builtin_amdgcn_global_load_lds(
      (const __attribute__((address_space(1))) unsigned int*)g,
      (__attribute__((address_space(3))) unsigned int*)l, 16, 0, 0);
}

struct GP {
  const unsigned short* A;
  const unsigned short* B;
  int M, N, K, lda, ldb, ldc;
  long sA, sB, sC;
  unsigned short* C;
  float* outF;
  const float* bias;
  unsigned short* q_out;
  unsigned short* k_out;
  unsigned short* vT_out;
};

// C = A @ B^T, A:[M,K] bf16 row-major(lda), B:[N,K] bf16 row-major(ldb).
// 4 waves, per-wave 64x64 via 4x4 frags of mfma_f32_16x16x32_bf16. BK=64.
// LDS XOR-swizzle achieved by pre-swizzling the GLOBAL chunk index and
// writing LDS linearly via global_load_lds (wave-uniform base + lane*16).
template<int WM, int WN, int EPI, int KS>
__global__ __launch_bounds__(256) void gemm_bt(GP p) {
  constexpr int BM = WM * 64, BN = WN * 64;
  __shared__ __align__(16) unsigned short lA[BM * 64];
  __shared__ __align__(16) unsigned short lB[BN * 64];
  const int tid = threadIdx.x, lane = tid & 63, wid = tid >> 6;
  const int wr = wid / WN, wc = wid % WN;
  const int m0 = blockIdx.y * BM, n0 = blockIdx.x * BN;
  const int bz = blockIdx.z;
  int bzh = bz, ksl = 0;
  if constexpr (KS > 1) { bzh = bz / KS; ksl = bz - bzh * KS; }
  const unsigned short* Ab = p.A + (long)bzh * p.sA;
  const unsigned short* Bb = p.B + (long)bzh * p.sB;
  const int kbeg = ksl * (p.K / KS), kend = kbeg + p.K / KS;

  f32x4 acc[4][4];
#pragma unroll
  for (int i = 0; i < 4; ++i)
#pragma unroll
    for (int j = 0; j < 4; ++j) acc[i][j] = (f32x4)0.f;

  for (int k0 = kbeg; k0 < kend; k0 += 64) {
    __syncthreads();
#pragma unroll
    for (int i = 0; i < BM / 32; ++i) {
      int c = tid + i * 256, r = c >> 3, kc = c & 7, kg = kc ^ (r & 7);
      gload16(Ab + (long)(m0 + r) * p.lda + k0 + kg * 8, &lA[c * 8]);
    }
#pragma unroll
    for (int i = 0; i < BN / 32; ++i) {
      int c = tid + i * 256, r = c >> 3, kc = c & 7, kg = kc ^ (r & 7);
      gload16(Bb + (long)(n0 + r) * p.ldb + k0 + kg * 8, &lB[c * 8]);
    }
    __syncthreads();
#pragma unroll
    for (int half = 0; half < 2; ++half) {
      bf16x8 af[4], bfr[4];
#pragma unroll
      for (int mi = 0; mi < 4; ++mi) {
        int r = wr * 64 + mi * 16 + (lane & 15);
        int kc = half * 4 + (lane >> 4);
        af[mi] = *(const bf16x8*)&lA[r * 64 + ((kc ^ (r & 7)) << 3)];
      }
#pragma unroll
      for (int ni = 0; ni < 4; ++ni) {
        int r = wc * 64 + ni * 16 + (lane & 15);
        int kc = half * 4 + (lane >> 4);
        bfr[ni] = *(const bf16x8*)&lB[r * 64 + ((kc ^ (r & 7)) << 3)];
      }
#pragma unroll
      for (int mi = 0; mi < 4; ++mi)
#pragma unroll
        for (int ni = 0; ni < 4; ++ni)
          acc[mi][ni] = __builtin_amdgcn_mfma_f32_16x16x32_bf16(
              af[mi], bfr[ni], acc[mi][ni], 0, 0, 0);
    }
  }

#pragma unroll
  for (int mi = 0; mi < 4; ++mi)
#pragma unroll
    for (int ni = 0; ni < 4; ++ni)
#pragma unroll
      for (int r2 = 0; r2 < 4; ++r2) {
        int row = m0 + wr * 64 + mi * 16 + (lane >> 4) * 4 + r2;
        int col = n0 + wc * 64 + ni * 16 + (lane & 15);
        float v = acc[mi][ni][r2];
        if constexpr (EPI == 0) {          // plain bf16 store
          p.C[(long)bzh * p.sC + (long)row * p.ldc + col] = f2bf(v);
        } else if constexpr (EPI == 1) {   // qkv scatter: q*SCALE, k, v^T
          int b = row >> 10, n = row & 1023;
          int s = col / 768, rem = col - s * 768;
          int h = rem >> 6, d = rem & 63;
          long ho = (long)(b * 12 + h);
          if (s == 0)      p.q_out[(ho * 1024 + n) * 64 + d] = f2bf(v * 0.125f);
          else if (s == 1) p.k_out[(ho * 1024 + n) * 64 + d] = f2bf(v);
          else             p.vT_out[(ho * 64 + d) * 1024 + n] = f2bf(v);
        } else if constexpr (EPI == 2) {   // fp32 out + bias
          p.outF[(long)row * p.ldc + col] = v + p.bias[col];
        } else if constexpr (EPI == 5) {   // split-K partial, U^T layout [d][n]
          atomicAdd(&p.outF[(long)bzh * 65536 + (long)row * 1024 + col], v);
        } else if constexpr (EPI == 6) {   // split-K partial, Y layout [n][d]
          atomicAdd(&p.outF[(long)bzh * 65536 + (long)row * 64 + col], v);
        }
      }
}

// One block per (b,n) row: pre-mix over heads -> softmax -> post-mix,
// register-resident: each thread owns 4 columns x 12 heads (L[12][4]).
__global__ __launch_bounds__(256) void mix_softmax(
    unsigned short* S, const float* W1, const float* b1,
    const float* W2, const float* b2) {
  __shared__ float w1s[144], w2s[144], b1s[12], b2s[12];
  __shared__ float red[4][12];
  const int tid = threadIdx.x, lane = tid & 63, wid = tid >> 6;
  if (tid < 144) { w1s[tid] = W1[tid]; w2s[tid] = W2[tid]; }
  if (tid < 12) { b1s[tid] = b1[tid]; b2s[tid] = b2[tid]; }
  const int bn = blockIdx.x;
  const int b = bn >> 10, n = bn & 1023;
  unsigned short* Sb = S + ((long)(b * 12) * 1024 + n) * 1024 + tid * 4;
  __syncthreads();

  float L[12][4];
#pragma unroll
  for (int g = 0; g < 12; ++g)
#pragma unroll
    for (int j = 0; j < 4; ++j) L[g][j] = b1s[g];
#pragma unroll
  for (int h = 0; h < 12; ++h) {
    ushort4 vv = *(const ushort4*)(Sb + (long)h * 1048576);
    float f0 = bf2f(vv.x), f1 = bf2f(vv.y), f2 = bf2f(vv.z), f3 = bf2f(vv.w);
#pragma unroll
    for (int g = 0; g < 12; ++g) {
      float w = w1s[g * 12 + h];
      L[g][0] += w * f0; L[g][1] += w * f1;
      L[g][2] += w * f2; L[g][3] += w * f3;
    }
  }
  float rv[12];
#pragma unroll
  for (int g = 0; g < 12; ++g) {
    float m = fmaxf(fmaxf(L[g][0], L[g][1]), fmaxf(L[g][2], L[g][3]));
#pragma unroll
    for (int o = 32; o > 0; o >>= 1) m = fmaxf(m, __shfl_xor(m, o));
    rv[g] = m;
  }
  if (lane == 0) {
#pragma unroll
    for (int g = 0; g < 12; ++g) red[wid][g] = rv[g];
  }
  __syncthreads();
  float mxf[12];
#pragma unroll
  for (int g = 0; g < 12; ++g)
    mxf[g] = fmaxf(fmaxf(red[0][g], red[1][g]), fmaxf(red[2][g], red[3][g]));
  __syncthreads();
#pragma unroll
  for (int g = 0; g < 12; ++g) {
    float s = 0.f;
#pragma unroll
    for (int j = 0; j < 4; ++j) {
      L[g][j] = __expf(L[g][j] - mxf[g]);
      s += L[g][j];
    }
#pragma unroll
    for (int o = 32; o > 0; o >>= 1) s += __shfl_xor(s, o);
    rv[g] = s;
  }
  if (lane == 0) {
#pragma unroll
    for (int g = 0; g < 12; ++g) red[wid][g] = rv[g];
  }
  __syncthreads();
#pragma unroll
  for (int g = 0; g < 12; ++g) {
    float rinv = 1.f / (red[0][g] + red[1][g] + red[2][g] + red[3][g]);
#pragma unroll
    for (int j = 0; j < 4; ++j) L[g][j] *= rinv;
  }
#pragma unroll
  for (int g = 0; g < 12; ++g) {
    float o0 = b2s[g], o1 = o0, o2 = o0, o3 = o0;
#pragma unroll
    for (int h = 0; h < 12; ++h) {
      float w = w2s[g * 12 + h];
      o0 += w * L[h][0]; o1 += w * L[h][1];
      o2 += w * L[h][2]; o3 += w * L[h][3];
    }
    uint2 ov = { pk_bf16(o0, o1), pk_bf16(o2, o3) };
    *(uint2*)(Sb + (long)g * 1048576) = ov;
  }
}

__global__ __launch_bounds__(256) void f2bf_vec(const float* in,
                                                unsigned short* out, int n4) {
  int i = blockIdx.x * blockDim.x + threadIdx.x;
  if (i < n4) {
    float4 v = *(const float4*)(in + (long)i * 4);
    uint2 o = { pk_bf16(v.x, v.y), pk_bf16(v.z, v.w) };
    *(uint2*)(out + (long)i * 4) = o;
  }
}

// ctx = (1-2λ)U + 3λ Y, scatter to [B,N,768] bf16.
// Uf layout [bz][d][n] (U^T), Yf layout [bz][n][d].
__global__ __launch_bounds__(256) void ctx_epi(const float* Uf, const float* Yf,
                                               const float* lamb,
                                               unsigned short* ctx) {
  int gid = blockIdx.x * 256 + threadIdx.x;   // 786432 quads
  int bz = gid >> 14;
  int rem = gid & 16383;
  int n = rem >> 4;
  int d0 = (rem & 15) * 4;
  int b = bz / 12, h = bz - b * 12;
  float lam = lamb[h];
  float a = 1.f - 2.f * lam, c3 = 3.f * lam;
  const float* Ub = Uf + (long)bz * 65536;
  float4 y = *(const float4*)(Yf + (long)bz * 65536 + n * 64 + d0);
  float c0 = a * Ub[(d0 + 0) * 1024 + n] + c3 * y.x;
  float c1 = a * Ub[(d0 + 1) * 1024 + n] + c3 * y.y;
  float c2 = a * Ub[(d0 + 2) * 1024 + n] + c3 * y.z;
  float cc = a * Ub[(d0 + 3) * 1024 + n] + c3 * y.w;
  uint2 ov = { pk_bf16(c0, c1), pk_bf16(c2, cc) };
  *(uint2*)(ctx + ((long)(b * 1024 + n)) * 768 + h * 64 + d0) = ov;
}

extern "C" void kernel_launch(void* const* d_in, const int* in_sizes, int n_in,
                              void* d_out, int out_size, void* d_ws,
                              size_t ws_size, hipStream_t stream) {
  const float* x     = (const float*)d_in[0];
  const float* qkv_w = (const float*)d_in[1];
  const float* W1    = (const float*)d_in[2];
  const float* b1    = (const float*)d_in[3];
  const float* W2    = (const float*)d_in[4];
  const float* b2    = (const float*)d_in[5];
  const float* lamb  = (const float*)d_in[6];
  const float* Wout  = (const float*)d_in[7];
  const float* bout  = (const float*)d_in[8];
  float* out = (float*)d_out;

  char* ws = (char*)d_ws;
  // Explicit layout (bytes). region1 (24 MiB) holds x/wqkv/q/k early, then is
  // reused (after GEMM2) for the fp32 split-K accumulators Uf/Yf.
  unsigned short* Sbuf = (unsigned short*)(ws);                  // 96 MiB
  char* r1 = ws + 100663296;                                     // 24 MiB
  unsigned short* x_bf    = (unsigned short*)(r1);               // 6 MiB
  unsigned short* wqkv_bf = (unsigned short*)(r1 + 6291456);     // 3.375 MiB
  unsigned short* q_bf    = (unsigned short*)(r1 + 9830400);     // 6 MiB
  unsigned short* k_bf    = (unsigned short*)(r1 + 16121856);    // 6 MiB
  float* Uf = (float*)(r1);                                      // 12 MiB
  float* Yf = (float*)(r1 + 12582912);                           // 12 MiB
  char* r2 = r1 + 25165824;
  unsigned short* vT_bf   = (unsigned short*)(r2);               // 6 MiB
  unsigned short* UT      = (unsigned short*)(r2 + 6291456);     // 6 MiB
  unsigned short* ctx     = (unsigned short*)(r2 + 12582912);    // 6 MiB
  unsigned short* wout_bf = (unsigned short*)(r2 + 18874368);    // 1.125 MiB
  size_t total = 100663296 + 25165824 + 18874368 + 1179648;
  if (total > ws_size) return;

  f2bf_vec<<<dim3(4096 * 768 / 4 / 256), 256, 0, stream>>>(x, x_bf, 4096 * 768 / 4);
  f2bf_vec<<<dim3(2304 * 768 / 4 / 256), 256, 0, stream>>>(qkv_w, wqkv_bf, 2304 * 768 / 4);
  f2bf_vec<<<dim3(768 * 768 / 4 / 256), 256, 0, stream>>>(Wout, wout_bf, 768 * 768 / 4);

  {  // GEMM1: qkv = x @ qkv_w^T, scatter q/k/vT
    GP p{};
    p.A = x_bf; p.B = wqkv_bf;
    p.M = 4096; p.N = 2304; p.K = 768; p.lda = 768; p.ldb = 768;
    p.q_out = q_bf; p.k_out = k_bf; p.vT_out = vT_bf;
    gemm_bt<2, 2, 1, 1><<<dim3(18, 32, 1), 256, 0, stream>>>(p);
  }
  {  // GEMM2: S[b,h] = q @ k^T   (48 batches)
    GP p{};
    p.A = q_bf; p.B = k_bf;
    p.M = 1024; p.N = 1024; p.K = 64; p.lda = 64; p.ldb = 64;
    p.sA = 65536; p.sB = 65536;
    p.C = Sbuf; p.sC = 1048576; p.ldc = 1024;
    gemm_bt<2, 2, 0, 1><<<dim3(8, 8, 48), 256, 0, stream>>>(p);
  }
  // q/k/x/wqkv now dead -> reuse region1 for split-K accumulators.
  hipMemsetAsync(Uf, 0, 12582912, stream);
  hipMemsetAsync(Yf, 0, 12582912, stream);
  mix_softmax<<<dim3(4096), 256, 0, stream>>>(Sbuf, W1, b1, W2, b2);
  {  // GEMM3: U^T[d][n] = vT @ A^T, split-K x4 -> atomic fp32
    GP p{};
    p.A = vT_bf; p.B = Sbuf;
    p.M = 64; p.N = 1024; p.K = 1024; p.lda = 1024; p.ldb = 1024;
    p.sA = 65536; p.sB = 1048576;
    p.outF = Uf;
    gemm_bt<1, 4, 5, 4><<<dim3(4, 1, 192), 256, 0, stream>>>(p);
  }
  f2bf_vec<<<dim3(3072), 256, 0, stream>>>(Uf, UT, 786432);
  {  // GEMM4: Y[n][d] = A @ U, split-K x4 -> atomic fp32
    GP p{};
    p.A = Sbuf; p.B = UT;
    p.M = 1024; p.N = 64; p.K = 1024; p.lda = 1024; p.ldb = 1024;
    p.sA = 1048576; p.sB = 65536;
    p.outF = Yf;
    gemm_bt<4, 1, 6, 4><<<dim3(1, 4, 192), 256, 0, stream>>>(p);
  }
  ctx_epi<<<dim3(3072), 256, 0, stream>>>(Uf, Yf, lamb, ctx);
  {  // GEMM5: out = ctx @ Wout^T + bout  (fp32 out)
    GP p{};
    p.A = ctx; p.B = wout_bf;
    p.M = 4096; p.N = 768; p.K = 768; p.lda = 768; p.ldb = 768;
    p.outF = out; p.bias = bout; p.ldc = 768;
    gemm_bt<2, 2, 2, 1><<<dim3(6, 32, 1), 256, 0, stream>>>(p);
  }
}

// Round 4
// 192.417 us; speedup vs baseline: 1.4946x; 1.4946x over previous
//
#include <hip/hip_runtime.h>
#include <hip/hip_bf16.h>

// Talking-heads attention + GFSA reaction, MI355X (gfx950).
//   attn_final = (1-2λ)A + 3λ A²  applied to v:
//   ctx = (1-2λ)(A@v) + 3λ A@(A@v)   -- never forms A@A.
// R3->R4: revert split-K atomics (regression); flexible-tile GEMM template
// (per-wave FMxFN frags) -> 768-block skinny GEMMs; LDS-staged coalesced
// C-stores for the 96MB S write; packed uint2 vT stores / U reads.

typedef __bf16 bf16x8 __attribute__((ext_vector_type(8)));
typedef float f32x4 __attribute__((ext_vector_type(4)));

#define DI __device__ __forceinline__

DI unsigned short f2bf(float f) {
  union { float f; unsigned u; } x; x.f = f;
  unsigned r = x.u + 0x7FFF + ((x.u >> 16) & 1);   // RNE
  return (unsigned short)(r >> 16);
}
DI float bf2f(unsigned short u) {
  union { unsigned u; float f; } x; x.u = ((unsigned)u) << 16; return x.f;
}
DI unsigned pk_bf16(float a, float b) {   // packs (a,b) -> 2xbf16, RNE
  unsigned r;
  asm("v_cvt_pk_bf16_f32 %0, %1, %2" : "=v"(r) : "v"(a), "v"(b));
  return r;
}
DI void gload16(const unsigned short* g, unsigned short* l) {
  __builtin_amdgcn_global_load_lds(
      (const __attribute__((address_space(1))) unsigned int*)g,
      (__attribute__((address_space(3))) unsigned int*)l, 16, 0, 0);
}

struct GP {
  const unsigned short* A;
  const unsigned short* B;
  int K, lda, ldb, ldc;
  long sA, sB, sC;
  unsigned short* C;
  const unsigned short* C2;
  float* outF;
  const float* bias;
  const float* lamb;
  unsigned short* q_out;
  unsigned short* k_out;
  unsigned short* vT_out;
};

// C = A @ B^T, A:[M,K] bf16 row-major(lda), B:[N,K] bf16 row-major(ldb).
// Wave grid WMxWN, per-wave FMxFN frags of mfma_f32_16x16x32_bf16.
// BM=WM*FM*16, BN=WN*FN*16. BK=64. LDS XOR-swizzle via pre-swizzled global
// chunk index + linear global_load_lds (16B).
template<int WM, int WN, int FM, int FN, int EPI, int STC>
__global__ __launch_bounds__(256) void gemm_bt(GP p) {
  constexpr int BM = WM * FM * 16, BN = WN * FN * 16;
  constexpr int LSZ = (BM * 64 + BN * 64) > (BM * BN) ? (BM * 64 + BN * 64)
                                                      : (BM * BN);
  __shared__ __align__(16) unsigned short ls[LSZ];
  unsigned short* lA = ls;
  unsigned short* lB = ls + BM * 64;
  const int tid = threadIdx.x, lane = tid & 63, wid = tid >> 6;
  const int wr = wid / WN, wc = wid % WN;
  const int m0 = blockIdx.y * BM, n0 = blockIdx.x * BN;
  const int bz = blockIdx.z;
  const unsigned short* Ab = p.A + (long)bz * p.sA;
  const unsigned short* Bb = p.B + (long)bz * p.sB;

  f32x4 acc[FM][FN];
#pragma unroll
  for (int i = 0; i < FM; ++i)
#pragma unroll
    for (int j = 0; j < FN; ++j) acc[i][j] = (f32x4)0.f;

  for (int k0 = 0; k0 < p.K; k0 += 64) {
    __syncthreads();
#pragma unroll
    for (int i = 0; i < BM / 32; ++i) {
      int c = tid + i * 256, r = c >> 3, kc = c & 7, kg = kc ^ (r & 7);
      gload16(Ab + (long)(m0 + r) * p.lda + k0 + kg * 8, &lA[c * 8]);
    }
#pragma unroll
    for (int i = 0; i < BN / 32; ++i) {
      int c = tid + i * 256, r = c >> 3, kc = c & 7, kg = kc ^ (r & 7);
      gload16(Bb + (long)(n0 + r) * p.ldb + k0 + kg * 8, &lB[c * 8]);
    }
    __syncthreads();
#pragma unroll
    for (int half = 0; half < 2; ++half) {
      bf16x8 af[FM], bfr[FN];
#pragma unroll
      for (int mi = 0; mi < FM; ++mi) {
        int r = wr * FM * 16 + mi * 16 + (lane & 15);
        int kc = half * 4 + (lane >> 4);
        af[mi] = *(const bf16x8*)&lA[r * 64 + ((kc ^ (r & 7)) << 3)];
      }
#pragma unroll
      for (int ni = 0; ni < FN; ++ni) {
        int r = wc * FN * 16 + ni * 16 + (lane & 15);
        int kc = half * 4 + (lane >> 4);
        bfr[ni] = *(const bf16x8*)&lB[r * 64 + ((kc ^ (r & 7)) << 3)];
      }
#pragma unroll
      for (int mi = 0; mi < FM; ++mi)
#pragma unroll
        for (int ni = 0; ni < FN; ++ni)
          acc[mi][ni] = __builtin_amdgcn_mfma_f32_16x16x32_bf16(
              af[mi], bfr[ni], acc[mi][ni], 0, 0, 0);
    }
  }

  if constexpr (STC == 1) {
    // Stage bf16 C-tile in LDS (chunk-XOR swizzle), then coalesced 16B writes.
    __syncthreads();
#pragma unroll
    for (int mi = 0; mi < FM; ++mi)
#pragma unroll
      for (int ni = 0; ni < FN; ++ni) {
        int row = wr * FM * 16 + mi * 16 + (lane >> 4) * 4;
        int col = wc * FN * 16 + ni * 16 + (lane & 15);
#pragma unroll
        for (int r2 = 0; r2 < 4; ++r2)
          ls[(row + r2) * BN + (col ^ ((row + r2) & 7) * 8)] =
              f2bf(acc[mi][ni][r2]);
      }
    __syncthreads();
    constexpr int CPR = BN / 8;           // 16B chunks per row
#pragma unroll
    for (int idx = tid; idx < BM * CPR; idx += 256) {
      int row = idx / CPR, cc = idx % CPR;
      uint4 d = *(const uint4*)&ls[row * BN + (cc ^ (row & 7)) * 8];
      *(uint4*)&p.C[(long)bz * p.sC + (long)(m0 + row) * p.ldc + n0 + cc * 8] = d;
    }
    return;
  }

#pragma unroll
  for (int mi = 0; mi < FM; ++mi)
#pragma unroll
    for (int ni = 0; ni < FN; ++ni) {
      const int rowb = m0 + wr * FM * 16 + mi * 16 + (lane >> 4) * 4;
      const int col = n0 + wc * FN * 16 + ni * 16 + (lane & 15);
      if constexpr (EPI == 1) {            // qkv scatter: q*SCALE, k, v^T
        int s = col / 768, rem = col - s * 768;
        int h = rem >> 6, d = rem & 63;
        int b = rowb >> 10, n = rowb & 1023;
        long ho = (long)(b * 12 + h);
        if (s == 2) {                      // 4 consecutive n -> one 8B store
          uint2 pk = { pk_bf16(acc[mi][ni][0], acc[mi][ni][1]),
                       pk_bf16(acc[mi][ni][2], acc[mi][ni][3]) };
          *(uint2*)&p.vT_out[(ho * 64 + d) * 1024 + n] = pk;
        } else {
#pragma unroll
          for (int r2 = 0; r2 < 4; ++r2) {
            float v = acc[mi][ni][r2];
            if (s == 0)
              p.q_out[(ho * 1024 + n + r2) * 64 + d] = f2bf(v * 0.125f);
            else
              p.k_out[(ho * 1024 + n + r2) * 64 + d] = f2bf(v);
          }
        }
      } else if constexpr (EPI == 2) {     // fp32 out + bias
        float bb = p.bias[col];
#pragma unroll
        for (int r2 = 0; r2 < 4; ++r2)
          p.outF[(long)(rowb + r2) * p.ldc + col] = acc[mi][ni][r2] + bb;
      } else if constexpr (EPI == 4) {     // ctx = (1-2λ)U + 3λ·Y
        int b = bz / 12, h = bz - b * 12;
        float lam = p.lamb[h];
        float a1 = 1.f - 2.f * lam, c3 = 3.f * lam;
        uint2 uq = *(const uint2*)&p.C2[(long)bz * 65536 + (long)col * 1024 + rowb];
        float uv[4] = { bf2f((unsigned short)(uq.x & 0xffff)),
                        bf2f((unsigned short)(uq.x >> 16)),
                        bf2f((unsigned short)(uq.y & 0xffff)),
                        bf2f((unsigned short)(uq.y >> 16)) };
#pragma unroll
        for (int r2 = 0; r2 < 4; ++r2) {
          float val = a1 * uv[r2] + c3 * acc[mi][ni][r2];
          p.C[((long)(b * 1024 + rowb + r2)) * 768 + h * 64 + col] = f2bf(val);
        }
      }
    }
}

// One block per (b,n) row: pre-mix over heads -> softmax -> post-mix,
// register-resident: each thread owns 4 columns x 12 heads (L[12][4]).
__global__ __launch_bounds__(256) void mix_softmax(
    unsigned short* S, const float* W1, const float* b1,
    const float* W2, const float* b2) {
  __shared__ float w1s[144], w2s[144], b1s[12], b2s[12];
  __shared__ float red[4][12];
  const int tid = threadIdx.x, lane = tid & 63, wid = tid >> 6;
  if (tid < 144) { w1s[tid] = W1[tid]; w2s[tid] = W2[tid]; }
  if (tid < 12) { b1s[tid] = b1[tid]; b2s[tid] = b2[tid]; }
  const int bn = blockIdx.x;
  const int b = bn >> 10, n = bn & 1023;
  unsigned short* Sb = S + ((long)(b * 12) * 1024 + n) * 1024 + tid * 4;
  __syncthreads();

  float L[12][4];
#pragma unroll
  for (int g = 0; g < 12; ++g)
#pragma unroll
    for (int j = 0; j < 4; ++j) L[g][j] = b1s[g];
#pragma unroll
  for (int h = 0; h < 12; ++h) {
    ushort4 vv = *(const ushort4*)(Sb + (long)h * 1048576);
    float f0 = bf2f(vv.x), f1 = bf2f(vv.y), f2 = bf2f(vv.z), f3 = bf2f(vv.w);
#pragma unroll
    for (int g = 0; g < 12; ++g) {
      float w = w1s[g * 12 + h];
      L[g][0] += w * f0; L[g][1] += w * f1;
      L[g][2] += w * f2; L[g][3] += w * f3;
    }
  }
  float rv[12];
#pragma unroll
  for (int g = 0; g < 12; ++g) {
    float m = fmaxf(fmaxf(L[g][0], L[g][1]), fmaxf(L[g][2], L[g][3]));
#pragma unroll
    for (int o = 32; o > 0; o >>= 1) m = fmaxf(m, __shfl_xor(m, o));
    rv[g] = m;
  }
  if (lane == 0) {
#pragma unroll
    for (int g = 0; g < 12; ++g) red[wid][g] = rv[g];
  }
  __syncthreads();
  float mxf[12];
#pragma unroll
  for (int g = 0; g < 12; ++g)
    mxf[g] = fmaxf(fmaxf(red[0][g], red[1][g]), fmaxf(red[2][g], red[3][g]));
  __syncthreads();
#pragma unroll
  for (int g = 0; g < 12; ++g) {
    float s = 0.f;
#pragma unroll
    for (int j = 0; j < 4; ++j) {
      L[g][j] = __expf(L[g][j] - mxf[g]);
      s += L[g][j];
    }
#pragma unroll
    for (int o = 32; o > 0; o >>= 1) s += __shfl_xor(s, o);
    rv[g] = s;
  }
  if (lane == 0) {
#pragma unroll
    for (int g = 0; g < 12; ++g) red[wid][g] = rv[g];
  }
  __syncthreads();
#pragma unroll
  for (int g = 0; g < 12; ++g) {
    float rinv = 1.f / (red[0][g] + red[1][g] + red[2][g] + red[3][g]);
#pragma unroll
    for (int j = 0; j < 4; ++j) L[g][j] *= rinv;
  }
#pragma unroll
  for (int g = 0; g < 12; ++g) {
    float o0 = b2s[g], o1 = o0, o2 = o0, o3 = o0;
#pragma unroll
    for (int h = 0; h < 12; ++h) {
      float w = w2s[g * 12 + h];
      o0 += w * L[h][0]; o1 += w * L[h][1];
      o2 += w * L[h][2]; o3 += w * L[h][3];
    }
    uint2 ov = { pk_bf16(o0, o1), pk_bf16(o2, o3) };
    *(uint2*)(Sb + (long)g * 1048576) = ov;
  }
}

// One kernel converting three fp32->bf16 regions (fewer graph nodes).
__global__ __launch_bounds__(256) void cvt3(
    const float* a, const float* b, const float* c,
    unsigned short* oa, unsigned short* ob, unsigned short* oc,
    int na, int nb, int nc) {
  int i = blockIdx.x * 256 + threadIdx.x;
  const float* src;
  unsigned short* dst;
  int j = i;
  if (i < na) { src = a; dst = oa; }
  else if (i < na + nb) { src = b; dst = ob; j = i - na; }
  else if (i < na + nb + nc) { src = c; dst = oc; j = i - na - nb; }
  else return;
  float4 v = *(const float4*)(src + (long)j * 4);
  uint2 o = { pk_bf16(v.x, v.y), pk_bf16(v.z, v.w) };
  *(uint2*)(dst + (long)j * 4) = o;
}

extern "C" void kernel_launch(void* const* d_in, const int* in_sizes, int n_in,
                              void* d_out, int out_size, void* d_ws,
                              size_t ws_size, hipStream_t stream) {
  const float* x     = (const float*)d_in[0];
  const float* qkv_w = (const float*)d_in[1];
  const float* W1    = (const float*)d_in[2];
  const float* b1    = (const float*)d_in[3];
  const float* W2    = (const float*)d_in[4];
  const float* b2    = (const float*)d_in[5];
  const float* lamb  = (const float*)d_in[6];
  const float* Wout  = (const float*)d_in[7];
  const float* bout  = (const float*)d_in[8];
  float* out = (float*)d_out;

  char* ws = (char*)d_ws;
  size_t off = 0;
  auto alloc = [&](size_t bytes) {
    char* p = ws + off;
    off = (off + bytes + 255) & ~(size_t)255;
    return p;
  };
  unsigned short* Sbuf    = (unsigned short*)alloc(48ull * 1024 * 1024 * 2);
  unsigned short* x_bf    = (unsigned short*)alloc(4096ull * 768 * 2);
  unsigned short* wqkv_bf = (unsigned short*)alloc(2304ull * 768 * 2);
  unsigned short* wout_bf = (unsigned short*)alloc(768ull * 768 * 2);
  unsigned short* q_bf    = (unsigned short*)alloc(48ull * 1024 * 64 * 2);
  unsigned short* k_bf    = (unsigned short*)alloc(48ull * 1024 * 64 * 2);
  unsigned short* vT_bf   = (unsigned short*)alloc(48ull * 64 * 1024 * 2);
  unsigned short* UT      = (unsigned short*)alloc(48ull * 64 * 1024 * 2);
  unsigned short* ctx     = (unsigned short*)alloc(4096ull * 768 * 2);
  if (off > ws_size) return;

  cvt3<<<dim3(5376), 256, 0, stream>>>(x, qkv_w, Wout, x_bf, wqkv_bf, wout_bf,
                                       786432, 442368, 147456);

  {  // GEMM1: qkv = x @ qkv_w^T, scatter q/k/vT  (128x128 tiles)
    GP p{};
    p.A = x_bf; p.B = wqkv_bf;
    p.K = 768; p.lda = 768; p.ldb = 768;
    p.q_out = q_bf; p.k_out = k_bf; p.vT_out = vT_bf;
    gemm_bt<2, 2, 4, 4, 1, 0><<<dim3(18, 32, 1), 256, 0, stream>>>(p);
  }
  {  // GEMM2: S[b,h] = q @ k^T (48 batches, 128x128, LDS-staged C store)
    GP p{};
    p.A = q_bf; p.B = k_bf;
    p.K = 64; p.lda = 64; p.ldb = 64;
    p.sA = 65536; p.sB = 65536;
    p.C = Sbuf; p.sC = 1048576; p.ldc = 1024;
    gemm_bt<2, 2, 4, 4, 0, 1><<<dim3(8, 8, 48), 256, 0, stream>>>(p);
  }
  mix_softmax<<<dim3(4096), 256, 0, stream>>>(Sbuf, W1, b1, W2, b2);
  {  // GEMM3: U^T[d][n] = vT @ A^T  (64x64 tiles -> 768 blocks)
    GP p{};
    p.A = vT_bf; p.B = Sbuf;
    p.K = 1024; p.lda = 1024; p.ldb = 1024;
    p.sA = 65536; p.sB = 1048576;
    p.C = UT; p.sC = 65536; p.ldc = 1024;
    gemm_bt<1, 4, 4, 1, 0, 1><<<dim3(16, 1, 48), 256, 0, stream>>>(p);
  }
  {  // GEMM4: Y = A @ U; ctx = (1-2λ)U + 3λY  (64x64 tiles -> 768 blocks)
    GP p{};
    p.A = Sbuf; p.B = UT;
    p.K = 1024; p.lda = 1024; p.ldb = 1024;
    p.sA = 1048576; p.sB = 65536;
    p.C = ctx; p.C2 = UT; p.lamb = lamb;
    gemm_bt<4, 1, 1, 4, 4, 0><<<dim3(1, 16, 48), 256, 0, stream>>>(p);
  }
  {  // GEMM5: out = ctx @ Wout^T + bout  (64x64 tiles -> 768 blocks, fp32 out)
    GP p{};
    p.A = ctx; p.B = wout_bf;
    p.K = 768; p.lda = 768; p.ldb = 768;
    p.outF = out; p.bias = bout; p.ldc = 768;
    gemm_bt<2, 2, 2, 2, 2, 0><<<dim3(12, 64, 1), 256, 0, stream>>>(p);
  }
}